// Round 1
// baseline (353.935 us; speedup 1.0000x reference)
//
#include <hip/hip_runtime.h>
#include <hip/hip_bf16.h>

// ---- problem constants ----
#define IN_CH    31
#define OUT_CH   31
#define NB       8
#define COEF_LEN 7688           // 31*31*8
#define NPIX     16384          // 128*128
#define KPAD     288            // 279 conv weights + 1 bias col + 8 zero pad
#define NCOLS    320            // 32 o-slots * 10 (8 coef + univ + res), o=31 is zero pad
#define NFRAG    20             // 320/16
#define KSTEPS   9              // 288/32
#define CHUNKS   31             // one per input channel
#define PLDS_STRIDE 296         // 288 + 8 pad (592B row stride: 16B aligned, bank-staggered)
#define CHT_STRIDE  68          // 64 + 4 pad
#define LDS_BYTES (NCOLS*CHT_STRIDE*4 + 64*PLDS_STRIDE*2)   // 87040 + 37888 = 124928

using f32x4 = __attribute__((ext_vector_type(4))) float;
using s16x8 = __attribute__((ext_vector_type(8))) short;

__device__ __forceinline__ unsigned short f2bf(float f) {
    unsigned int u = __float_as_uint(f);
    unsigned int r = (u + 0x7FFFu + ((u >> 16) & 1u)) >> 16;
    return (unsigned short)r;
}

// ---------------------------------------------------------------------------
// Pack gen_w/gen_b into bf16 B-fragment layout:
//   Bpack[i][nf][ks][lane][8]   (16B per lane -> one coalesced dwordx4 load)
// column c = nf*16 + (lane&15); o = c/10, j = c%10
//   j in 0..7 -> coef[i][o][j]; j==8 -> univ[i][o]; j==9 -> res[i][o]
// k = ks*32 + (lane>>4)*8 + jj; k<279 -> gen_w[p][k]; k==279 -> gen_b[p]; else 0
// ---------------------------------------------------------------------------
__global__ void pack_kernel(const float* __restrict__ gw, const float* __restrict__ gb,
                            unsigned short* __restrict__ bp) {
    int tt = blockIdx.x * 256 + threadIdx.x;
    if (tt >= CHUNKS * NFRAG * KSTEPS * 64) return;
    int lane = tt & 63;
    int t2 = tt >> 6;
    int ks = t2 % KSTEPS;
    int t3 = t2 / KSTEPS;
    int nf = t3 % NFRAG;
    int i  = t3 / NFRAG;

    int c = nf * 16 + (lane & 15);
    int o = c / 10, j = c - o * 10;
    int kbase = ks * 32 + (lane >> 4) * 8;

    int p = -1;
    if (o < OUT_CH) {
        if (j < 8)       p = i * 248 + o * 8 + j;
        else if (j == 8) p = COEF_LEN + i * 31 + o;
        else             p = COEF_LEN + 961 + i * 31 + o;
    }
    s16x8 v;
    #pragma unroll
    for (int jj = 0; jj < 8; ++jj) {
        int k = kbase + jj;
        float val = 0.f;
        if (p >= 0) {
            if (k < 279)       val = gw[p * 279 + k];
            else if (k == 279) val = gb[p];
        }
        v[jj] = (short)f2bf(val);
    }
    *reinterpret_cast<s16x8*>(bp + (size_t)tt * 8) = v;
}

// ---------------------------------------------------------------------------
// Fused conv-GEMM + KAN epilogue.
// Block = 64 pixels (half an image row), 512 threads = 8 waves (2M x 4N).
// Per chunk i: GEMM 64x320x288 bf16 MFMA -> LDS (transposed) -> epilogue
// accumulates out[n][o] in registers using closed-form cubic B-spline weights.
// ---------------------------------------------------------------------------
__global__ void __launch_bounds__(512, 1)
main_kernel(const float* __restrict__ x, const unsigned short* __restrict__ bp,
            float* __restrict__ out) {
    extern __shared__ char smem[];
    float* chT = (float*)smem;                                  // [NCOLS][68] f32
    unsigned short* plds = (unsigned short*)(smem + NCOLS * CHT_STRIDE * 4); // [64][296] bf16
    float* xs = (float*)smem;                                   // alias: [31][3][68] staging

    const int tid = threadIdx.x;
    const int pix_base = blockIdx.x * 64;
    const int h0 = pix_base >> 7;
    const int w0 = pix_base & 127;

    // phase 0: stage x slab (rows h0-1..h0+1, cols w0-1..w0+64, zero-padded)
    for (int idx = tid; idx < 31 * 3 * 66; idx += 512) {
        int ci = idx / 198;
        int rem = idx - ci * 198;
        int ry = rem / 66;
        int cx = rem - ry * 66;
        int hh = h0 - 1 + ry;
        int ww = w0 - 1 + cx;
        float v = 0.f;
        if ((unsigned)hh < 128u && (unsigned)ww < 128u)
            v = x[ci * NPIX + hh * 128 + ww];
        xs[(ci * 3 + ry) * CHT_STRIDE + cx] = v;
    }
    __syncthreads();

    // phase 1: build bf16 patch tile plds[n][k], k=(ci*9+ky*3+kx), col 279 = 1.0 (bias)
    for (int idx = tid; idx < 64 * KPAD; idx += 512) {
        int n = idx / KPAD;
        int k = idx - n * KPAD;
        unsigned short val = 0;
        if (k < 279) {
            int ci = k / 9;
            int r = k - ci * 9;
            int ky = r / 3;
            int kx = r - ky * 3;
            val = f2bf(xs[(ci * 3 + ky) * CHT_STRIDE + n + kx]);
        } else if (k == 279) {
            val = 0x3F80;  // 1.0f in bf16
        }
        plds[n * PLDS_STRIDE + k] = val;
    }
    __syncthreads();

    const int lane = tid & 63;
    const int wave = tid >> 6;
    const int wm = wave >> 2;   // 0..1  (M split)
    const int wn = wave & 3;    // 0..3  (N split)

    // epilogue mapping: pixel n = lane, outputs o = wave + 8k
    float oacc[4] = {0.f, 0.f, 0.f, 0.f};

    int a_base[2];
    #pragma unroll
    for (int mf = 0; mf < 2; ++mf)
        a_base[mf] = (wm * 32 + mf * 16 + (lane & 15)) * PLDS_STRIDE + (lane >> 4) * 8;

    const unsigned short* bwave = bp + (size_t)(wn * 5) * KSTEPS * 512;
    const int lane8 = lane * 8;

    #pragma unroll 1
    for (int i = 0; i < CHUNKS; ++i) {
        f32x4 acc[2][5];
        #pragma unroll
        for (int mf = 0; mf < 2; ++mf)
            #pragma unroll
            for (int nf = 0; nf < 5; ++nf)
                acc[mf][nf] = (f32x4){0.f, 0.f, 0.f, 0.f};

        const unsigned short* bchunk = bwave + (size_t)i * (NFRAG * KSTEPS * 512);
        #pragma unroll
        for (int ks = 0; ks < KSTEPS; ++ks) {
            s16x8 a[2];
            #pragma unroll
            for (int mf = 0; mf < 2; ++mf)
                a[mf] = *reinterpret_cast<const s16x8*>(plds + a_base[mf] + ks * 32);
            #pragma unroll
            for (int nf = 0; nf < 5; ++nf) {
                s16x8 b = *reinterpret_cast<const s16x8*>(bchunk + nf * (KSTEPS * 512) + ks * 512 + lane8);
                acc[0][nf] = __builtin_amdgcn_mfma_f32_16x16x32_bf16(a[0], b, acc[0][nf], 0, 0, 0);
                acc[1][nf] = __builtin_amdgcn_mfma_f32_16x16x32_bf16(a[1], b, acc[1][nf], 0, 0, 0);
            }
        }

        __syncthreads();   // previous epilogue finished reading chT
        // dump accumulators: chT[col][row], 4 rows contiguous -> f32x4, conflict-free
        #pragma unroll
        for (int mf = 0; mf < 2; ++mf) {
            int row = wm * 32 + mf * 16 + (lane >> 4) * 4;
            #pragma unroll
            for (int nf = 0; nf < 5; ++nf) {
                int col = wn * 80 + nf * 16 + (lane & 15);
                *reinterpret_cast<f32x4*>(chT + col * CHT_STRIDE + row) = acc[mf][nf];
            }
        }
        __syncthreads();

        // epilogue: closed-form cubic B-spline (4 active bases), silu residual
        float xv = x[i * NPIX + pix_base + lane];
        float u = (xv + 1.0f) * 2.5f;
        float cf = floorf(u);
        cf = fminf(fmaxf(cf, 0.f), 4.f);
        int cc = (int)cf;
        float t = u - cf;
        float omt = 1.f - t;
        float t2v = t * t, t3v = t2v * t;
        float bw0 = omt * omt * omt * (1.f / 6.f);
        float bw1 = (3.f * t3v - 6.f * t2v + 4.f) * (1.f / 6.f);
        float bw2 = (-3.f * t3v + 3.f * t2v + 3.f * t + 1.f) * (1.f / 6.f);
        float bw3 = t3v * (1.f / 6.f);
        float sl = xv / (1.f + __expf(-xv));

        #pragma unroll
        for (int kk = 0; kk < 4; ++kk) {
            int o = wave + 8 * kk;
            if (o < OUT_CH) {
                const float* basep = chT + (o * 10) * CHT_STRIDE + lane;
                float sp = bw0 * basep[(cc + 0) * CHT_STRIDE]
                         + bw1 * basep[(cc + 1) * CHT_STRIDE]
                         + bw2 * basep[(cc + 2) * CHT_STRIDE]
                         + bw3 * basep[(cc + 3) * CHT_STRIDE];
                float uv = basep[8 * CHT_STRIDE];
                float rv = basep[9 * CHT_STRIDE];
                oacc[kk] += uv * sp + sl * rv;
            }
        }
    }

    // write out: (1, 31, 128, 128) -> out[o*NPIX + pix]
    #pragma unroll
    for (int kk = 0; kk < 4; ++kk) {
        int o = wave + 8 * kk;
        if (o < OUT_CH)
            out[o * NPIX + pix_base + lane] = oacc[kk];
    }
}

extern "C" void kernel_launch(void* const* d_in, const int* in_sizes, int n_in,
                              void* d_out, int out_size, void* d_ws, size_t ws_size,
                              hipStream_t stream) {
    const float* x  = (const float*)d_in[0];   // (1,31,128,128)
    const float* gw = (const float*)d_in[1];   // (9610,31,3,3)
    const float* gb = (const float*)d_in[2];   // (9610,)
    float* outp = (float*)d_out;               // (1,31,128,128)
    unsigned short* bpack = (unsigned short*)d_ws;  // 5,713,920 bytes

    hipFuncSetAttribute((const void*)main_kernel,
                        hipFuncAttributeMaxDynamicSharedMemorySize, LDS_BYTES);

    pack_kernel<<<1395, 256, 0, stream>>>(gw, gb, bpack);
    main_kernel<<<256, 512, LDS_BYTES, stream>>>(x, bpack, outp);
}